// Round 1
// baseline (2256.484 us; speedup 1.0000x reference)
//
#include <hip/hip_runtime.h>
#include <cfloat>
#include <cmath>

#define N_P 50000
#define N_W 10000
#define D_P 256
#define D_W 128
#define HID 64
#define OUTD 8
#define KH 4
#define LL 2
#define E_PP 500000
#define E_PW 150000
#define E_WP 150000

__device__ inline float atomicMaxFloat(float* addr, float value) {
    if (value >= 0.f)
        return __int_as_float(atomicMax((int*)addr, __float_as_int(value)));
    else
        return __uint_as_float(atomicMin((unsigned int*)addr, __float_as_uint(value)));
}

// C[M,N] = A[M,Kd] @ B[Kd,N] (+ bias). N must divide 256. 256 threads/block.
__global__ void gemm_bias_kernel(const float* __restrict__ A, const float* __restrict__ B,
                                 const float* __restrict__ bias, float* __restrict__ C,
                                 int M, int Kd, int N) {
    int rpb = 256 / N;
    int r = blockIdx.x * rpb + threadIdx.x / N;
    int c = threadIdx.x % N;
    if (r >= M) return;
    float acc = bias ? bias[c] : 0.f;
    const float* a = A + (size_t)r * Kd;
    for (int k = 0; k < Kd; ++k) acc = fmaf(a[k], B[(size_t)k * N + c], acc);
    C[(size_t)r * N + c] = acc;
}

// wv[lt][j,k] = sum_h W[lt][j, k*64+h] * att[lt][k,h].  grid = L*3, block = 256.
__global__ void wv_kernel(const float* __restrict__ W, const float* __restrict__ att,
                          float* __restrict__ wv) {
    int lt = blockIdx.x;
    int j = threadIdx.x >> 2, k = threadIdx.x & 3;
    const float* Wp = W + (size_t)lt * HID * (KH * HID) + (size_t)j * (KH * HID) + k * HID;
    const float* ap = att + (size_t)lt * KH * HID + k * HID;
    float s = 0.f;
    for (int h = 0; h < HID; ++h) s += Wp[h] * ap[h];
    wv[(size_t)lt * HID * KH + j * KH + k] = s;
}

// o[n*64+h] = b1[h] + (b2 ? b2[h] : 0)
__global__ void init_out_kernel(float* __restrict__ o, const float* __restrict__ b1,
                                const float* __restrict__ b2, int total) {
    int i = blockIdx.x * blockDim.x + threadIdx.x;
    if (i >= total) return;
    int h = i & (HID - 1);
    o[i] = b1[h] + (b2 ? b2[h] : 0.f);
}

__global__ void reset_md_kernel(float* __restrict__ m, float* __restrict__ den, int n) {
    int i = blockIdx.x * blockDim.x + threadIdx.x;
    if (i < n) { m[i] = -FLT_MAX; den[i] = 0.f; }
}

__device__ inline float edge_logit(const float* a_s, const float* a_d, int s, int d, int k) {
    float v = a_s[s * KH + k] + a_d[d * KH + k];
    return v > 0.f ? v : 0.2f * v;
}

__global__ void edge_max_kernel(const int* __restrict__ src, const int* __restrict__ dst,
                                const float* __restrict__ a_s, const float* __restrict__ a_d,
                                float* __restrict__ m, int E) {
    int i = blockIdx.x * blockDim.x + threadIdx.x;
    if (i >= E * KH) return;
    int e = i >> 2, k = i & 3;
    float v = edge_logit(a_s, a_d, src[e], dst[e], k);
    atomicMaxFloat(&m[dst[e] * KH + k], v);
}

__global__ void edge_sum_kernel(const int* __restrict__ src, const int* __restrict__ dst,
                                const float* __restrict__ a_s, const float* __restrict__ a_d,
                                const float* __restrict__ m, float* __restrict__ den, int E) {
    int i = blockIdx.x * blockDim.x + threadIdx.x;
    if (i >= E * KH) return;
    int e = i >> 2, k = i & 3;
    int d = dst[e];
    float v = edge_logit(a_s, a_d, src[e], d, k);
    atomicAdd(&den[d * KH + k], expf(v - m[d * KH + k]));
}

// one 64-lane wave per edge; lane = feature h
__global__ void edge_msg_kernel(const int* __restrict__ src, const int* __restrict__ dst,
                                const float* __restrict__ a_s, const float* __restrict__ a_d,
                                const float* __restrict__ m, const float* __restrict__ den,
                                const float* __restrict__ hs, float* __restrict__ o, int E) {
    int gid = blockIdx.x * blockDim.x + threadIdx.x;
    int e = gid >> 6;
    int h = gid & 63;
    if (e >= E) return;
    int s = src[e], d = dst[e];
    float acc = 0.f;
#pragma unroll
    for (int k = 0; k < KH; ++k) {
        float v = edge_logit(a_s, a_d, s, d, k);
        float alpha = expf(v - m[d * KH + k]) / den[d * KH + k];
        acc += alpha * hs[(size_t)s * (KH * HID) + k * HID + h];
    }
    atomicAdd(&o[(size_t)d * HID + h], 0.25f * acc);
}

__global__ void elu_update_kernel(const float* __restrict__ o, float* __restrict__ h,
                                  float scale, int n) {
    int i = blockIdx.x * blockDim.x + threadIdx.x;
    if (i < n) {
        float x = scale * o[i];
        h[i] = x > 0.f ? x : expf(x) - 1.f;
    }
}

extern "C" void kernel_launch(void* const* d_in, const int* in_sizes, int n_in,
                              void* d_out, int out_size, void* d_ws, size_t ws_size,
                              hipStream_t stream) {
    const float* x_p    = (const float*)d_in[0];
    const float* x_w    = (const float*)d_in[1];
    const float* Wpp    = (const float*)d_in[2];
    const float* bpp    = (const float*)d_in[3];
    const float* Wpw    = (const float*)d_in[4];
    const float* bpw    = (const float*)d_in[5];
    const float* Wsrc   = (const float*)d_in[6];   // (2,3,64,256)
    const float* Wdst   = (const float*)d_in[7];   // (2,3,64,256)
    const float* Asrc   = (const float*)d_in[8];   // (2,3,4,64)
    const float* Adst   = (const float*)d_in[9];   // (2,3,4,64)
    const float* cbias  = (const float*)d_in[10];  // (2,3,64)
    const float* Wpostp = (const float*)d_in[11];
    const float* bpostp = (const float*)d_in[12];
    const float* Wpostw = (const float*)d_in[13];
    const float* bpostw = (const float*)d_in[14];
    const int*   ei_pp  = (const int*)d_in[15];    // (2, E_PP): src then dst
    const int*   ei_pw  = (const int*)d_in[16];
    const int*   ei_wp  = (const int*)d_in[17];

    float* ws = (float*)d_ws;
    float* h_p  = ws; ws += (size_t)N_P * HID;
    float* h_w  = ws; ws += (size_t)N_W * HID;
    float* o_p  = ws; ws += (size_t)N_P * HID;
    float* o_w  = ws; ws += (size_t)N_W * HID;
    float* hs   = ws; ws += (size_t)N_P * KH * HID;
    float* a_s  = ws; ws += (size_t)N_P * KH;
    float* a_d  = ws; ws += (size_t)N_P * KH;
    float* mbuf = ws; ws += (size_t)N_P * KH;
    float* den  = ws; ws += (size_t)N_P * KH;
    float* wv_s = ws; ws += (size_t)LL * 3 * HID * KH;
    float* wv_d = ws; ws += (size_t)LL * 3 * HID * KH;

    auto cdiv = [](long long a, long long b) { return (int)((a + b - 1) / b); };

    // precompute attention-weight vectors (removes hd entirely)
    wv_kernel<<<LL * 3, 256, 0, stream>>>(Wsrc, Asrc, wv_s);
    wv_kernel<<<LL * 3, 256, 0, stream>>>(Wdst, Adst, wv_d);

    // input projections
    gemm_bias_kernel<<<cdiv(N_P, 4), 256, 0, stream>>>(x_p, Wpp, bpp, h_p, N_P, D_P, HID);
    gemm_bias_kernel<<<cdiv(N_W, 4), 256, 0, stream>>>(x_w, Wpw, bpw, h_w, N_W, D_W, HID);

    for (int l = 0; l < LL; ++l) {
        init_out_kernel<<<cdiv((long long)N_P * HID, 256), 256, 0, stream>>>(
            o_p, cbias + (l * 3 + 0) * HID, cbias + (l * 3 + 2) * HID, N_P * HID);
        init_out_kernel<<<cdiv((long long)N_W * HID, 256), 256, 0, stream>>>(
            o_w, cbias + (l * 3 + 1) * HID, nullptr, N_W * HID);

        struct GatDesc { const float* hsrc; const float* hdst; int Ns, Nd, E; const int* ei; float* out; };
        GatDesc gats[3] = {
            { h_p, h_p, N_P, N_P, E_PP, ei_pp, o_p },
            { h_p, h_w, N_P, N_W, E_PW, ei_pw, o_w },
            { h_w, h_p, N_W, N_P, E_WP, ei_wp, o_p },
        };
        for (int t = 0; t < 3; ++t) {
            int lt = l * 3 + t;
            GatDesc& g = gats[t];
            const float* Ws = Wsrc + (size_t)lt * HID * KH * HID;
            // hs = h_src @ W_src[l,t]  -> [Ns, 256]
            gemm_bias_kernel<<<g.Ns, 256, 0, stream>>>(g.hsrc, Ws, nullptr, hs, g.Ns, HID, KH * HID);
            // a_s = h_src @ wv_s[lt], a_d = h_dst @ wv_d[lt]  -> [N, 4]
            gemm_bias_kernel<<<cdiv(g.Ns, 64), 256, 0, stream>>>(
                g.hsrc, wv_s + (size_t)lt * HID * KH, nullptr, a_s, g.Ns, HID, KH);
            gemm_bias_kernel<<<cdiv(g.Nd, 64), 256, 0, stream>>>(
                g.hdst, wv_d + (size_t)lt * HID * KH, nullptr, a_d, g.Nd, HID, KH);
            reset_md_kernel<<<cdiv((long long)g.Nd * KH, 256), 256, 0, stream>>>(mbuf, den, g.Nd * KH);
            const int* src = g.ei;
            const int* dst = g.ei + g.E;
            edge_max_kernel<<<cdiv((long long)g.E * KH, 256), 256, 0, stream>>>(src, dst, a_s, a_d, mbuf, g.E);
            edge_sum_kernel<<<cdiv((long long)g.E * KH, 256), 256, 0, stream>>>(src, dst, a_s, a_d, mbuf, den, g.E);
            edge_msg_kernel<<<cdiv((long long)g.E * 64, 256), 256, 0, stream>>>(src, dst, a_s, a_d, mbuf, den, hs, g.out, g.E);
        }
        elu_update_kernel<<<cdiv((long long)N_P * HID, 256), 256, 0, stream>>>(o_p, h_p, 0.5f, N_P * HID);
        elu_update_kernel<<<cdiv((long long)N_W * HID, 256), 256, 0, stream>>>(o_w, h_w, 1.0f, N_W * HID);
    }

    float* out_p = (float*)d_out;
    float* out_w = out_p + (size_t)N_P * OUTD;
    gemm_bias_kernel<<<cdiv(N_P, 32), 256, 0, stream>>>(h_p, Wpostp, bpostp, out_p, N_P, HID, OUTD);
    gemm_bias_kernel<<<cdiv(N_W, 32), 256, 0, stream>>>(h_w, Wpostw, bpostw, out_w, N_W, HID, OUTD);
}

// Round 2
// 966.460 us; speedup vs baseline: 2.3348x; 2.3348x over previous
//
#include <hip/hip_runtime.h>
#include <cfloat>
#include <cmath>

#define N_P 50000
#define N_W 10000
#define D_P 256
#define D_W 128
#define HID 64
#define OUTD 8
#define KH 4
#define LL 2
#define E_PP 500000
#define E_PW 150000
#define E_WP 150000

__device__ inline float atomicMaxFloat(float* addr, float value) {
    if (value >= 0.f)
        return __int_as_float(atomicMax((int*)addr, __float_as_int(value)));
    else
        return __uint_as_float(atomicMin((unsigned int*)addr, __float_as_uint(value)));
}

// ---------------------------------------------------------------------------
// Tiled register-blocked GEMM: C[M,N] = A[M,K] @ B[K,N] (+bias).
// 256 threads. Each thread: TM rows x 4 cols. A staged transposed in LDS.
// N in {64, 256}; K multiple of 64.
// ---------------------------------------------------------------------------
template<int N, int TM>
__global__ __launch_bounds__(256) void gemm_tiled(const float* __restrict__ A,
                                                  const float* __restrict__ B,
                                                  const float* __restrict__ bias,
                                                  float* __restrict__ C,
                                                  int M, int K) {
    constexpr int CG = N / 4;        // threads per row-group (each thread 4 cols)
    constexpr int RG = 256 / CG;     // row-groups per block
    constexpr int ROWS = RG * TM;    // rows per block
    constexpr int KC = 64;           // K-chunk
    __shared__ float As[KC * ROWS];  // transposed: As[k][row]

    int tid = threadIdx.x;
    int cg = tid % CG;
    int rg = tid / CG;
    int r_base = blockIdx.x * ROWS;
    int row0 = rg * TM;

    float acc[TM][4];
#pragma unroll
    for (int m = 0; m < TM; ++m)
#pragma unroll
        for (int j = 0; j < 4; ++j) acc[m][j] = 0.f;

    for (int kc = 0; kc < K; kc += KC) {
        __syncthreads();
        // stage A[r_base..r_base+ROWS][kc..kc+KC] transposed into LDS
        constexpr int LOADS = ROWS * KC / (4 * 256);
#pragma unroll
        for (int it = 0; it < LOADS; ++it) {
            int f4 = it * 256 + tid;
            int i = f4 % ROWS;        // row within tile
            int j4 = f4 / ROWS;       // float4 index within K-chunk
            int grow = r_base + i;
            float4 a4 = make_float4(0.f, 0.f, 0.f, 0.f);
            if (grow < M) a4 = *(const float4*)&A[(size_t)grow * K + kc + j4 * 4];
            As[(j4 * 4 + 0) * ROWS + i] = a4.x;
            As[(j4 * 4 + 1) * ROWS + i] = a4.y;
            As[(j4 * 4 + 2) * ROWS + i] = a4.z;
            As[(j4 * 4 + 3) * ROWS + i] = a4.w;
        }
        __syncthreads();

        const float4* B4 = (const float4*)(B + (size_t)kc * N) + cg;
#pragma unroll
        for (int k = 0; k < KC; ++k) {
            float4 b = B4[(size_t)k * CG];
#pragma unroll
            for (int m4 = 0; m4 < TM / 4; ++m4) {
                float4 a = *(const float4*)&As[k * ROWS + row0 + m4 * 4];
                float av[4] = {a.x, a.y, a.z, a.w};
#pragma unroll
                for (int mm = 0; mm < 4; ++mm) {
                    int m = m4 * 4 + mm;
                    acc[m][0] = fmaf(av[mm], b.x, acc[m][0]);
                    acc[m][1] = fmaf(av[mm], b.y, acc[m][1]);
                    acc[m][2] = fmaf(av[mm], b.z, acc[m][2]);
                    acc[m][3] = fmaf(av[mm], b.w, acc[m][3]);
                }
            }
        }
    }

    float4 bv = make_float4(0.f, 0.f, 0.f, 0.f);
    if (bias) bv = *(const float4*)&bias[cg * 4];
#pragma unroll
    for (int m = 0; m < TM; ++m) {
        int grow = r_base + row0 + m;
        if (grow < M) {
            float4 o;
            o.x = acc[m][0] + bv.x;
            o.y = acc[m][1] + bv.y;
            o.z = acc[m][2] + bv.z;
            o.w = acc[m][3] + bv.w;
            *(float4*)&C[(size_t)grow * N + cg * 4] = o;
        }
    }
}

// ---------------------------------------------------------------------------
// Small-N GEMM: out[n, 0:NC] = h[n, 0:64] @ W[64, NC] (+bias). 1 thread/node.
// ---------------------------------------------------------------------------
template<int NC>
__global__ void av_kernel(const float* __restrict__ h, const float* __restrict__ W,
                          const float* __restrict__ bias, float* __restrict__ out, int M) {
    int n = blockIdx.x * blockDim.x + threadIdx.x;
    if (n >= M) return;
    const float4* h4 = (const float4*)(h + (size_t)n * HID);
    float acc[NC];
#pragma unroll
    for (int c = 0; c < NC; ++c) acc[c] = bias ? bias[c] : 0.f;
#pragma unroll
    for (int k4 = 0; k4 < HID / 4; ++k4) {
        float4 hv = h4[k4];
#pragma unroll
        for (int c = 0; c < NC; ++c) {
            acc[c] = fmaf(hv.x, W[(k4 * 4 + 0) * NC + c], acc[c]);
            acc[c] = fmaf(hv.y, W[(k4 * 4 + 1) * NC + c], acc[c]);
            acc[c] = fmaf(hv.z, W[(k4 * 4 + 2) * NC + c], acc[c]);
            acc[c] = fmaf(hv.w, W[(k4 * 4 + 3) * NC + c], acc[c]);
        }
    }
#pragma unroll
    for (int c4 = 0; c4 < NC / 4; ++c4) {
        float4 o = make_float4(acc[c4 * 4 + 0], acc[c4 * 4 + 1], acc[c4 * 4 + 2], acc[c4 * 4 + 3]);
        *(float4*)&out[(size_t)n * NC + c4 * 4] = o;
    }
}

// wv[lt][j,k] = sum_h W[lt][j, k*64+h] * att[lt][k,h].  grid = L*3, block = 256.
__global__ void wv_kernel(const float* __restrict__ W, const float* __restrict__ att,
                          float* __restrict__ wv) {
    int lt = blockIdx.x;
    int j = threadIdx.x >> 2, k = threadIdx.x & 3;
    const float* Wp = W + (size_t)lt * HID * (KH * HID) + (size_t)j * (KH * HID) + k * HID;
    const float* ap = att + (size_t)lt * KH * HID + k * HID;
    float s = 0.f;
    for (int h = 0; h < HID; ++h) s += Wp[h] * ap[h];
    wv[(size_t)lt * HID * KH + j * KH + k] = s;
}

// o[n*64+h] = b1[h] + (b2 ? b2[h] : 0)
__global__ void init_out_kernel(float* __restrict__ o, const float* __restrict__ b1,
                                const float* __restrict__ b2, int total) {
    int i = blockIdx.x * blockDim.x + threadIdx.x;
    if (i >= total) return;
    int h = i & (HID - 1);
    o[i] = b1[h] + (b2 ? b2[h] : 0.f);
}

__global__ void reset_md_kernel(float* __restrict__ m, float* __restrict__ den, int n) {
    int i = blockIdx.x * blockDim.x + threadIdx.x;
    if (i < n) { m[i] = -FLT_MAX; den[i] = 0.f; }
}

__device__ inline float edge_logit(const float* a_s, const float* a_d, int s, int d, int k) {
    float v = a_s[s * KH + k] + a_d[d * KH + k];
    return v > 0.f ? v : 0.2f * v;
}

__global__ void edge_max_kernel(const int* __restrict__ src, const int* __restrict__ dst,
                                const float* __restrict__ a_s, const float* __restrict__ a_d,
                                float* __restrict__ m, int E) {
    int i = blockIdx.x * blockDim.x + threadIdx.x;
    if (i >= E * KH) return;
    int e = i >> 2, k = i & 3;
    float v = edge_logit(a_s, a_d, src[e], dst[e], k);
    atomicMaxFloat(&m[dst[e] * KH + k], v);
}

__global__ void edge_sum_kernel(const int* __restrict__ src, const int* __restrict__ dst,
                                const float* __restrict__ a_s, const float* __restrict__ a_d,
                                const float* __restrict__ m, float* __restrict__ den, int E) {
    int i = blockIdx.x * blockDim.x + threadIdx.x;
    if (i >= E * KH) return;
    int e = i >> 2, k = i & 3;
    int d = dst[e];
    float v = edge_logit(a_s, a_d, src[e], d, k);
    atomicAdd(&den[d * KH + k], expf(v - m[d * KH + k]));
}

// one 64-lane wave per edge; lane = feature h
__global__ void edge_msg_kernel(const int* __restrict__ src, const int* __restrict__ dst,
                                const float* __restrict__ a_s, const float* __restrict__ a_d,
                                const float* __restrict__ m, const float* __restrict__ den,
                                const float* __restrict__ hs, float* __restrict__ o, int E) {
    int gid = blockIdx.x * blockDim.x + threadIdx.x;
    int e = gid >> 6;
    int h = gid & 63;
    if (e >= E) return;
    int s = src[e], d = dst[e];
    float acc = 0.f;
#pragma unroll
    for (int k = 0; k < KH; ++k) {
        float v = edge_logit(a_s, a_d, s, d, k);
        float alpha = expf(v - m[d * KH + k]) / den[d * KH + k];
        acc += alpha * hs[(size_t)s * (KH * HID) + k * HID + h];
    }
    atomicAdd(&o[(size_t)d * HID + h], 0.25f * acc);
}

__global__ void elu_update_kernel(const float* __restrict__ o, float* __restrict__ h,
                                  float scale, int n) {
    int i = blockIdx.x * blockDim.x + threadIdx.x;
    if (i < n) {
        float x = scale * o[i];
        h[i] = x > 0.f ? x : expf(x) - 1.f;
    }
}

extern "C" void kernel_launch(void* const* d_in, const int* in_sizes, int n_in,
                              void* d_out, int out_size, void* d_ws, size_t ws_size,
                              hipStream_t stream) {
    const float* x_p    = (const float*)d_in[0];
    const float* x_w    = (const float*)d_in[1];
    const float* Wpp    = (const float*)d_in[2];
    const float* bpp    = (const float*)d_in[3];
    const float* Wpw    = (const float*)d_in[4];
    const float* bpw    = (const float*)d_in[5];
    const float* Wsrc   = (const float*)d_in[6];   // (2,3,64,256)
    const float* Wdst   = (const float*)d_in[7];   // (2,3,64,256)
    const float* Asrc   = (const float*)d_in[8];   // (2,3,4,64)
    const float* Adst   = (const float*)d_in[9];   // (2,3,4,64)
    const float* cbias  = (const float*)d_in[10];  // (2,3,64)
    const float* Wpostp = (const float*)d_in[11];
    const float* bpostp = (const float*)d_in[12];
    const float* Wpostw = (const float*)d_in[13];
    const float* bpostw = (const float*)d_in[14];
    const int*   ei_pp  = (const int*)d_in[15];    // (2, E_PP): src then dst
    const int*   ei_pw  = (const int*)d_in[16];
    const int*   ei_wp  = (const int*)d_in[17];

    float* ws = (float*)d_ws;
    float* h_p  = ws; ws += (size_t)N_P * HID;
    float* h_w  = ws; ws += (size_t)N_W * HID;
    float* o_p  = ws; ws += (size_t)N_P * HID;
    float* o_w  = ws; ws += (size_t)N_W * HID;
    float* hs   = ws; ws += (size_t)N_P * KH * HID;
    float* a_s  = ws; ws += (size_t)N_P * KH;
    float* a_d  = ws; ws += (size_t)N_P * KH;
    float* mbuf = ws; ws += (size_t)N_P * KH;
    float* den  = ws; ws += (size_t)N_P * KH;
    float* wv_s = ws; ws += (size_t)LL * 3 * HID * KH;
    float* wv_d = ws; ws += (size_t)LL * 3 * HID * KH;

    auto cdiv = [](long long a, long long b) { return (int)((a + b - 1) / b); };

    // precompute attention-weight vectors (removes hd entirely)
    wv_kernel<<<LL * 3, 256, 0, stream>>>(Wsrc, Asrc, wv_s);
    wv_kernel<<<LL * 3, 256, 0, stream>>>(Wdst, Adst, wv_d);

    // input projections: N=64, TM=8 -> 128 rows/block
    gemm_tiled<64, 8><<<cdiv(N_P, 128), 256, 0, stream>>>(x_p, Wpp, bpp, h_p, N_P, D_P);
    gemm_tiled<64, 8><<<cdiv(N_W, 128), 256, 0, stream>>>(x_w, Wpw, bpw, h_w, N_W, D_W);

    for (int l = 0; l < LL; ++l) {
        init_out_kernel<<<cdiv((long long)N_P * HID, 256), 256, 0, stream>>>(
            o_p, cbias + (l * 3 + 0) * HID, cbias + (l * 3 + 2) * HID, N_P * HID);
        init_out_kernel<<<cdiv((long long)N_W * HID, 256), 256, 0, stream>>>(
            o_w, cbias + (l * 3 + 1) * HID, nullptr, N_W * HID);

        struct GatDesc { const float* hsrc; const float* hdst; int Ns, Nd, E; const int* ei; float* out; };
        GatDesc gats[3] = {
            { h_p, h_p, N_P, N_P, E_PP, ei_pp, o_p },
            { h_p, h_w, N_P, N_W, E_PW, ei_pw, o_w },
            { h_w, h_p, N_W, N_P, E_WP, ei_wp, o_p },
        };
        for (int t = 0; t < 3; ++t) {
            int lt = l * 3 + t;
            GatDesc& g = gats[t];
            const float* Ws = Wsrc + (size_t)lt * HID * KH * HID;
            // hs = h_src @ W_src[l,t]  -> [Ns, 256]; N=256, TM=8 -> 32 rows/block
            gemm_tiled<256, 8><<<cdiv(g.Ns, 32), 256, 0, stream>>>(g.hsrc, Ws, nullptr, hs, g.Ns, HID);
            // a_s = h_src @ wv_s[lt], a_d = h_dst @ wv_d[lt]  -> [N, 4]
            av_kernel<4><<<cdiv(g.Ns, 256), 256, 0, stream>>>(
                g.hsrc, wv_s + (size_t)lt * HID * KH, nullptr, a_s, g.Ns);
            av_kernel<4><<<cdiv(g.Nd, 256), 256, 0, stream>>>(
                g.hdst, wv_d + (size_t)lt * HID * KH, nullptr, a_d, g.Nd);
            reset_md_kernel<<<cdiv((long long)g.Nd * KH, 256), 256, 0, stream>>>(mbuf, den, g.Nd * KH);
            const int* src = g.ei;
            const int* dst = g.ei + g.E;
            edge_max_kernel<<<cdiv((long long)g.E * KH, 256), 256, 0, stream>>>(src, dst, a_s, a_d, mbuf, g.E);
            edge_sum_kernel<<<cdiv((long long)g.E * KH, 256), 256, 0, stream>>>(src, dst, a_s, a_d, mbuf, den, g.E);
            edge_msg_kernel<<<cdiv((long long)g.E * 64, 256), 256, 0, stream>>>(src, dst, a_s, a_d, mbuf, den, hs, g.out, g.E);
        }
        elu_update_kernel<<<cdiv((long long)N_P * HID, 256), 256, 0, stream>>>(o_p, h_p, 0.5f, N_P * HID);
        elu_update_kernel<<<cdiv((long long)N_W * HID, 256), 256, 0, stream>>>(o_w, h_w, 1.0f, N_W * HID);
    }

    float* out_p = (float*)d_out;
    float* out_w = out_p + (size_t)N_P * OUTD;
    av_kernel<8><<<cdiv(N_P, 256), 256, 0, stream>>>(h_p, Wpostp, bpostp, out_p, N_P);
    av_kernel<8><<<cdiv(N_W, 256), 256, 0, stream>>>(h_w, Wpostw, bpostw, out_w, N_W);
}